// Round 1
// baseline (465.694 us; speedup 1.0000x reference)
//
#include <hip/hip_runtime.h>

// ---------- types ----------
typedef short  short8  __attribute__((ext_vector_type(8)));   // 8 x bf16 payload (4 VGPR)
typedef float  f32x4   __attribute__((ext_vector_type(4)));
typedef ushort u16x4   __attribute__((ext_vector_type(4)));

__device__ __forceinline__ float bf2f(ushort u) {
  union { unsigned u; float f; } v; v.u = ((unsigned)u) << 16; return v.f;
}
__device__ __forceinline__ ushort f2bf(float f) {
  union { float f; unsigned u; } v; v.f = f;
  unsigned r = v.u + 0x7FFF + ((v.u >> 16) & 1);   // RNE
  return (ushort)(r >> 16);
}

// async global->LDS, 16B per lane; LDS dest = wave-uniform base + lane*16
__device__ __forceinline__ void gload16(const ushort* g, ushort* l) {
  __builtin_amdgcn_global_load_lds(
      (__attribute__((address_space(1))) void*)(void*)(const_cast<ushort*>(g)),
      (__attribute__((address_space(3))) void*)(void*)l, 16, 0, 0);
}

// ---------- sizes ----------
// B=4 S=2048 E=1024 H=16 D=64 ; M = B*S = 8192 ; K = 1024

// ---------- 1. prep: x -> xt,xs bf16 ; out plane1 = xs fp32 ----------
__global__ __launch_bounds__(256) void prep_x(const float* __restrict__ x,
                                              ushort* __restrict__ xt,
                                              ushort* __restrict__ xs,
                                              float* __restrict__ out) {
  size_t i = ((size_t)blockIdx.x * 256 + threadIdx.x) * 4;   // over 8192*1024
  size_t m = i >> 10, e = i & 1023;
  f32x4 a = *(const f32x4*)&x[m * 2048 + e];          // xt row (plane 0)
  f32x4 b = *(const f32x4*)&x[m * 2048 + 1024 + e];   // xs row (plane 1)
  u16x4 ta, tb;
#pragma unroll
  for (int j = 0; j < 4; ++j) { ta[j] = f2bf(a[j]); tb[j] = f2bf(b[j]); }
  *(u16x4*)&xt[i] = ta;
  *(u16x4*)&xs[i] = tb;
  *(f32x4*)&out[m * 2048 + 1024 + e] = b;             // exact passthrough
}

// ---------- 2. weight transpose: W [K][N] f32 -> Wt [N][K] bf16 ----------
__global__ __launch_bounds__(256) void transpose_w(const float* __restrict__ W,
                                                   ushort* __restrict__ Wt,
                                                   int K, int N) {
  __shared__ float tile[32][33];
  int n0 = blockIdx.x * 32, k0 = blockIdx.y * 32;
  int tx = threadIdx.x & 31, ty = threadIdx.x >> 5;   // 32 x 8
#pragma unroll
  for (int i = 0; i < 32; i += 8)
    tile[ty + i][tx] = W[(size_t)(k0 + ty + i) * N + n0 + tx];
  __syncthreads();
#pragma unroll
  for (int i = 0; i < 32; i += 8)
    Wt[(size_t)(n0 + ty + i) * K + k0 + tx] = f2bf(tile[tx][ty + i]);
}

// ---------- 3. GEMM (m97 structure): C[m][n] = sum_k A[m][k]*Bt[n][k] ----------
// 128x128 tile, BK=32, 4 waves (2x2), each wave 64x64 via 4x4 16x16x32 MFMA.
template <int F32OUT>
__global__ __launch_bounds__(256) void gemm_bt(const ushort* __restrict__ A,
                                               const ushort* __restrict__ Bt,
                                               ushort* __restrict__ Cb,
                                               float* __restrict__ Cf,
                                               int N, int ldc) {
  const int K = 1024;
  __shared__ ushort sA[128 * 32];
  __shared__ ushort sB[128 * 32];
  const int tid = threadIdx.x;
  const int wave = tid >> 6, lane = tid & 63;
  const int wr = wave >> 1, wc = wave & 1;
  const int l15 = lane & 15, l4 = lane >> 4;
  const int m0 = blockIdx.y * 128, n0 = blockIdx.x * 128;

  f32x4 acc[4][4];
  const f32x4 z = {0.f, 0.f, 0.f, 0.f};
#pragma unroll
  for (int a = 0; a < 4; ++a)
#pragma unroll
    for (int b = 0; b < 4; ++b) acc[a][b] = z;

  for (int k0 = 0; k0 < K; k0 += 32) {
#pragma unroll
    for (int j = 0; j < 2; ++j) {
      int cb = j * 256 + wave * 64;       // uniform chunk base
      int c = cb + lane;
      int row = c >> 2, cc = c & 3;       // 4 x 16B chunks per 32-elem row
      gload16(&A [(size_t)(m0 + row) * K + k0 + cc * 8], &sA[cb * 8]);
      gload16(&Bt[(size_t)(n0 + row) * K + k0 + cc * 8], &sB[cb * 8]);
    }
    __syncthreads();                      // drains vmcnt -> LDS valid
    short8 af[4], bfr[4];
#pragma unroll
    for (int i = 0; i < 4; ++i) {
      af[i]  = *(const short8*)&sA[(wr * 64 + i * 16 + l15) * 32 + l4 * 8];
      bfr[i] = *(const short8*)&sB[(wc * 64 + i * 16 + l15) * 32 + l4 * 8];
    }
#pragma unroll
    for (int mi = 0; mi < 4; ++mi)
#pragma unroll
      for (int ni = 0; ni < 4; ++ni)
        acc[mi][ni] = __builtin_amdgcn_mfma_f32_16x16x32_bf16(af[mi], bfr[ni], acc[mi][ni], 0, 0, 0);
    __syncthreads();                      // all reads done before restage
  }

#pragma unroll
  for (int mi = 0; mi < 4; ++mi)
#pragma unroll
    for (int ni = 0; ni < 4; ++ni) {
      int row = m0 + wr * 64 + mi * 16 + l4 * 4;
      int col = n0 + wc * 64 + ni * 16 + l15;
#pragma unroll
      for (int r = 0; r < 4; ++r) {
        if constexpr (F32OUT) Cf[(size_t)(row + r) * ldc + col] = acc[mi][ni][r];
        else                  Cb[(size_t)(row + r) * ldc + col] = f2bf(acc[mi][ni][r]);
      }
    }
}

// ---------- 4. scatter: build Q=[qt|qs]*scale, K=[kt+lts*ks | lst*kt+lss*ks] ----------
// layouts: Qb/Kb [B][H][S][128] bf16
__global__ __launch_bounds__(256) void scatter_qk(const ushort* __restrict__ Ct,
                                                  const ushort* __restrict__ Cs,
                                                  ushort* __restrict__ Qb,
                                                  ushort* __restrict__ Kb,
                                                  const float* plts, const float* plst,
                                                  const float* plss) {
  int tid = blockIdx.x * 256 + threadIdx.x;   // 8192 * 128
  int m = tid >> 7, u = tid & 127;
  int b = m >> 11, s = m & 2047;
  int h = u >> 3, din = (u & 7) * 8;
  float lts = plts[0], lst = plst[0], lss = plss[0];
  const float scale = 0.125f;                 // 1/sqrt(64)
  short8 qt = *(const short8*)&Ct[(size_t)m * 3072 + u * 8];
  short8 kt = *(const short8*)&Ct[(size_t)m * 3072 + 1024 + u * 8];
  short8 qs = *(const short8*)&Cs[(size_t)m * 2048 + u * 8];
  short8 ks = *(const short8*)&Cs[(size_t)m * 2048 + 1024 + u * 8];
  short8 oqt, oqs, k1, k2;
#pragma unroll
  for (int j = 0; j < 8; ++j) {
    float fqt = bf2f((ushort)qt[j]), fqs = bf2f((ushort)qs[j]);
    float fkt = bf2f((ushort)kt[j]), fks = bf2f((ushort)ks[j]);
    oqt[j] = (short)f2bf(fqt * scale);
    oqs[j] = (short)f2bf(fqs * scale);
    k1[j]  = (short)f2bf(fkt + lts * fks);
    k2[j]  = (short)f2bf(lst * fkt + lss * fks);
  }
  size_t base = ((size_t)(b * 16 + h) * 2048 + s) * 128;
  *(short8*)&Qb[base + din]      = oqt;
  *(short8*)&Qb[base + 64 + din] = oqs;
  *(short8*)&Kb[base + din]      = k1;
  *(short8*)&Kb[base + 64 + din] = k2;
}

// ---------- 5. V transpose: Ct vt cols -> Vt [B][H][64][S] bf16 ----------
__global__ __launch_bounds__(256) void transpose_v(const ushort* __restrict__ Ct,
                                                   ushort* __restrict__ Vt) {
  int bh = blockIdx.y; int s0 = blockIdx.x * 64;
  int b = bh >> 4, h = bh & 15;
  __shared__ ushort t[64][72];
  int tid = threadIdx.x;
#pragma unroll
  for (int j = 0; j < 2; ++j) {
    int c = j * 256 + tid;                 // 512 chunks of 8 elems
    int srow = c >> 3, cc = c & 7;
    *(short8*)&t[srow][cc * 8] =
        *(const short8*)&Ct[(size_t)(b * 2048 + s0 + srow) * 3072 + 2048 + h * 64 + cc * 8];
  }
  __syncthreads();
#pragma unroll
  for (int j = 0; j < 2; ++j) {
    int c = j * 256 + tid;
    int drow = c >> 3, cc = c & 7;
    short8 v;
#pragma unroll
    for (int k = 0; k < 8; ++k) v[k] = t[cc * 8 + k][drow];
    *(short8*)&Vt[((size_t)bh * 64 + drow) * 2048 + s0 + cc * 8] = v;
  }
}

// ---------- 6. flash attention: Q[S][128] x K[S][128] x Vt[64][S] -> Y[m][1024] ----------
// grid (S/64, B*H); 4 waves, wave w owns q rows q0+w*16..+16; KV tile 64 in LDS.
__global__ __launch_bounds__(256) void attn_kernel(const ushort* __restrict__ Q,
                                                   const ushort* __restrict__ K,
                                                   const ushort* __restrict__ V,
                                                   ushort* __restrict__ Y) {
  const int bh = blockIdx.y;
  const int q0 = blockIdx.x * 64;
  const int tid = threadIdx.x;
  const int wave = tid >> 6, lane = tid & 63;
  const int l15 = lane & 15, l4 = lane >> 4;
  const size_t qkb = (size_t)bh * 2048 * 128;
  const size_t vb  = (size_t)bh * 64 * 2048;

  __shared__ ushort sK[64 * 136];     // [kv][128] pad->136: 2-way banks only
  __shared__ ushort sV[64 * 72];      // [d][64] pad->72
  __shared__ ushort sP[4][16 * 72];   // per-wave P 16x64 pad->72

  short8 qf[4];
  {
    int qrow = q0 + wave * 16 + l15;
#pragma unroll
    for (int kk = 0; kk < 4; ++kk)
      qf[kk] = *(const short8*)&Q[qkb + (size_t)qrow * 128 + kk * 32 + l4 * 8];
  }
  const f32x4 z = {0.f, 0.f, 0.f, 0.f};
  f32x4 accO[4] = {z, z, z, z};
  float mrow[4], lrow[4];
#pragma unroll
  for (int r = 0; r < 4; ++r) { mrow[r] = -1e30f; lrow[r] = 0.f; }

  for (int kv0 = 0; kv0 < 2048; kv0 += 64) {
    __syncthreads();                         // prev tile's readers done
#pragma unroll
    for (int j = 0; j < 4; ++j) {            // stage K tile 64x128
      int c = j * 256 + tid;
      int row = c >> 4, cc = c & 15;
      *(short8*)&sK[row * 136 + cc * 8] =
          *(const short8*)&K[qkb + (size_t)(kv0 + row) * 128 + cc * 8];
    }
#pragma unroll
    for (int j = 0; j < 2; ++j) {            // stage V tile [64d][64s]
      int c = j * 256 + tid;
      int row = c >> 3, cc = c & 7;
      *(short8*)&sV[row * 72 + cc * 8] =
          *(const short8*)&V[vb + (size_t)row * 2048 + kv0 + cc * 8];
    }
    __syncthreads();

    f32x4 sc[4] = {z, z, z, z};              // S tile: rows=q, cols=kv (4x16)
#pragma unroll
    for (int kk = 0; kk < 4; ++kk)
#pragma unroll
      for (int kb = 0; kb < 4; ++kb) {
        short8 kf = *(const short8*)&sK[(kb * 16 + l15) * 136 + kk * 32 + l4 * 8];
        sc[kb] = __builtin_amdgcn_mfma_f32_16x16x32_bf16(qf[kk], kf, sc[kb], 0, 0, 0);
      }

    // online softmax (rows r live in 16-lane groups sharing l4)
#pragma unroll
    for (int r = 0; r < 4; ++r) {
      float mx = fmaxf(fmaxf(sc[0][r], sc[1][r]), fmaxf(sc[2][r], sc[3][r]));
#pragma unroll
      for (int off = 1; off < 16; off <<= 1) mx = fmaxf(mx, __shfl_xor(mx, off));
      float mnew = fmaxf(mrow[r], mx);
      float corr = __expf(mrow[r] - mnew);
      mrow[r] = mnew;
      lrow[r] *= corr;
#pragma unroll
      for (int nf = 0; nf < 4; ++nf) accO[nf][r] *= corr;
#pragma unroll
      for (int kb = 0; kb < 4; ++kb) {
        float p = __expf(sc[kb][r] - mnew);
        lrow[r] += p;                        // per-lane partial; reduce at end
        sP[wave][(l4 * 4 + r) * 72 + kb * 16 + l15] = f2bf(p);
      }
    }

    // PV: A = P (16q x 64kv) from sP, B = V (64kv x 64d) from sV
    short8 pf[2];
#pragma unroll
    for (int ks = 0; ks < 2; ++ks)
      pf[ks] = *(const short8*)&sP[wave][l15 * 72 + ks * 32 + l4 * 8];
#pragma unroll
    for (int nf = 0; nf < 4; ++nf)
#pragma unroll
      for (int ks = 0; ks < 2; ++ks) {
        short8 vf = *(const short8*)&sV[(nf * 16 + l15) * 72 + ks * 32 + l4 * 8];
        accO[nf] = __builtin_amdgcn_mfma_f32_16x16x32_bf16(pf[ks], vf, accO[nf], 0, 0, 0);
      }
  }

#pragma unroll
  for (int r = 0; r < 4; ++r) {
    float s = lrow[r];
#pragma unroll
    for (int off = 1; off < 16; off <<= 1) s += __shfl_xor(s, off);
    lrow[r] = 1.f / s;
  }
  int b = bh >> 4, hh = bh & 15;
#pragma unroll
  for (int nf = 0; nf < 4; ++nf)
#pragma unroll
    for (int r = 0; r < 4; ++r) {
      int q = q0 + wave * 16 + l4 * 4 + r;
      Y[((size_t)b * 2048 + q) * 1024 + hh * 64 + nf * 16 + l15] =
          f2bf(accO[nf][r] * lrow[r]);
    }
}

// ---------- launcher ----------
extern "C" void kernel_launch(void* const* d_in, const int* in_sizes, int n_in,
                              void* d_out, int out_size, void* d_ws, size_t ws_size,
                              hipStream_t stream) {
  const float* x   = (const float*)d_in[0];
  const float* Wt  = (const float*)d_in[1];
  const float* Ws  = (const float*)d_in[2];
  const float* Wo  = (const float*)d_in[3];
  const float* lts = (const float*)d_in[4];
  const float* lst = (const float*)d_in[5];
  const float* lss = (const float*)d_in[6];
  float* out = (float*)d_out;
  char* ws = (char*)d_ws;

  // workspace layout (bytes); Qbuf aliases xt+xs (dead after GEMMs),
  // Ybuf aliases Ct head (dead after scatter+transpose_v).
  ushort* xt    = (ushort*)(ws + 0);           // 16,777,216
  ushort* xs    = (ushort*)(ws + 16777216);    // 16,777,216
  ushort* Qbuf  = (ushort*)(ws + 0);           // 33,554,432 (alias)
  ushort* Wt_bt = (ushort*)(ws + 33554432);    //  6,291,456
  ushort* Ws_bt = (ushort*)(ws + 39845888);    //  4,194,304
  ushort* Wo_bt = (ushort*)(ws + 44040192);    //  2,097,152
  ushort* Ct    = (ushort*)(ws + 46137344);    // 50,331,648
  ushort* Ybuf  = (ushort*)(ws + 46137344);    // 16,777,216 (alias)
  ushort* Cs    = (ushort*)(ws + 96468992);    // 33,554,432
  ushort* Kbuf  = (ushort*)(ws + 130023424);   // 33,554,432
  ushort* Vtbuf = (ushort*)(ws + 163577856);   // 16,777,216  -> total 180,355,072
  (void)in_sizes; (void)n_in; (void)out_size; (void)ws_size;

  prep_x<<<8192, 256, 0, stream>>>(x, xt, xs, out);
  transpose_w<<<dim3(96, 32), 256, 0, stream>>>(Wt, Wt_bt, 1024, 3072);
  transpose_w<<<dim3(64, 32), 256, 0, stream>>>(Ws, Ws_bt, 1024, 2048);
  transpose_w<<<dim3(32, 32), 256, 0, stream>>>(Wo, Wo_bt, 1024, 1024);
  gemm_bt<0><<<dim3(24, 64), 256, 0, stream>>>(xt, Wt_bt, Ct, nullptr, 3072, 3072);
  gemm_bt<0><<<dim3(16, 64), 256, 0, stream>>>(xs, Ws_bt, Cs, nullptr, 2048, 2048);
  scatter_qk<<<4096, 256, 0, stream>>>(Ct, Cs, Qbuf, Kbuf, lts, lst, lss);
  transpose_v<<<dim3(32, 64), 256, 0, stream>>>(Ct, Vtbuf);
  attn_kernel<<<dim3(32, 64), 256, 0, stream>>>(Qbuf, Kbuf, Vtbuf, Ybuf);
  gemm_bt<1><<<dim3(8, 64), 256, 0, stream>>>(Ybuf, Wo_bt, nullptr, out, 1024, 2048);
}

// Round 2
// 403.984 us; speedup vs baseline: 1.1528x; 1.1528x over previous
//
#include <hip/hip_runtime.h>

// ---------- types ----------
typedef short  short8  __attribute__((ext_vector_type(8)));   // 8 x bf16 payload (4 VGPR)
typedef float  f32x4   __attribute__((ext_vector_type(4)));
typedef ushort u16x4   __attribute__((ext_vector_type(4)));

__device__ __forceinline__ float bf2f(ushort u) {
  union { unsigned u; float f; } v; v.u = ((unsigned)u) << 16; return v.f;
}
__device__ __forceinline__ ushort f2bf(float f) {
  union { float f; unsigned u; } v; v.f = f;
  unsigned r = v.u + 0x7FFF + ((v.u >> 16) & 1);   // RNE
  return (ushort)(r >> 16);
}

// async global->LDS, 16B per lane; LDS dest = wave-uniform base + lane*16
__device__ __forceinline__ void gload16(const ushort* g, ushort* l) {
  __builtin_amdgcn_global_load_lds(
      (__attribute__((address_space(1))) void*)(void*)(const_cast<ushort*>(g)),
      (__attribute__((address_space(3))) void*)(void*)l, 16, 0, 0);
}

// ---------- sizes ----------
// B=4 S=2048 E=1024 H=16 D=64 ; M = B*S = 8192 ; K = 1024

// ---------- 1. prep: x -> xt,xs bf16 ; out plane1 = xs fp32 ----------
__global__ __launch_bounds__(256) void prep_x(const float* __restrict__ x,
                                              ushort* __restrict__ xt,
                                              ushort* __restrict__ xs,
                                              float* __restrict__ out) {
  size_t i = ((size_t)blockIdx.x * 256 + threadIdx.x) * 4;   // over 8192*1024
  size_t m = i >> 10, e = i & 1023;
  f32x4 a = *(const f32x4*)&x[m * 2048 + e];          // xt row (plane 0)
  f32x4 b = *(const f32x4*)&x[m * 2048 + 1024 + e];   // xs row (plane 1)
  u16x4 ta, tb;
#pragma unroll
  for (int j = 0; j < 4; ++j) { ta[j] = f2bf(a[j]); tb[j] = f2bf(b[j]); }
  *(u16x4*)&xt[i] = ta;
  *(u16x4*)&xs[i] = tb;
  *(f32x4*)&out[m * 2048 + 1024 + e] = b;             // exact passthrough
}

// ---------- 2. weight transpose: W [K][N] f32 -> Wt [N][K] bf16 ----------
__global__ __launch_bounds__(256) void transpose_w(const float* __restrict__ W,
                                                   ushort* __restrict__ Wt,
                                                   int K, int N) {
  __shared__ float tile[32][33];
  int n0 = blockIdx.x * 32, k0 = blockIdx.y * 32;
  int tx = threadIdx.x & 31, ty = threadIdx.x >> 5;   // 32 x 8
#pragma unroll
  for (int i = 0; i < 32; i += 8)
    tile[ty + i][tx] = W[(size_t)(k0 + ty + i) * N + n0 + tx];
  __syncthreads();
#pragma unroll
  for (int i = 0; i < 32; i += 8)
    Wt[(size_t)(n0 + ty + i) * K + k0 + tx] = f2bf(tile[tx][ty + i]);
}

// ---------- 3. GEMM (m97 structure): C[m][n] = sum_k A[m][k]*Bt[n][k] ----------
template <int F32OUT>
__global__ __launch_bounds__(256) void gemm_bt(const ushort* __restrict__ A,
                                               const ushort* __restrict__ Bt,
                                               ushort* __restrict__ Cb,
                                               float* __restrict__ Cf,
                                               int N, int ldc) {
  const int K = 1024;
  __shared__ ushort sA[128 * 32];
  __shared__ ushort sB[128 * 32];
  const int tid = threadIdx.x;
  const int wave = tid >> 6, lane = tid & 63;
  const int wr = wave >> 1, wc = wave & 1;
  const int l15 = lane & 15, l4 = lane >> 4;
  const int m0 = blockIdx.y * 128, n0 = blockIdx.x * 128;

  f32x4 acc[4][4];
  const f32x4 z = {0.f, 0.f, 0.f, 0.f};
#pragma unroll
  for (int a = 0; a < 4; ++a)
#pragma unroll
    for (int b = 0; b < 4; ++b) acc[a][b] = z;

  for (int k0 = 0; k0 < K; k0 += 32) {
#pragma unroll
    for (int j = 0; j < 2; ++j) {
      int cb = j * 256 + wave * 64;       // uniform chunk base
      int c = cb + lane;
      int row = c >> 2, cc = c & 3;       // 4 x 16B chunks per 32-elem row
      gload16(&A [(size_t)(m0 + row) * K + k0 + cc * 8], &sA[cb * 8]);
      gload16(&Bt[(size_t)(n0 + row) * K + k0 + cc * 8], &sB[cb * 8]);
    }
    __syncthreads();                      // drains vmcnt -> LDS valid
    short8 af[4], bfr[4];
#pragma unroll
    for (int i = 0; i < 4; ++i) {
      af[i]  = *(const short8*)&sA[(wr * 64 + i * 16 + l15) * 32 + l4 * 8];
      bfr[i] = *(const short8*)&sB[(wc * 64 + i * 16 + l15) * 32 + l4 * 8];
    }
#pragma unroll
    for (int mi = 0; mi < 4; ++mi)
#pragma unroll
      for (int ni = 0; ni < 4; ++ni)
        acc[mi][ni] = __builtin_amdgcn_mfma_f32_16x16x32_bf16(af[mi], bfr[ni], acc[mi][ni], 0, 0, 0);
    __syncthreads();                      // all reads done before restage
  }

#pragma unroll
  for (int mi = 0; mi < 4; ++mi)
#pragma unroll
    for (int ni = 0; ni < 4; ++ni) {
      int row = m0 + wr * 64 + mi * 16 + l4 * 4;
      int col = n0 + wc * 64 + ni * 16 + l15;
#pragma unroll
      for (int r = 0; r < 4; ++r) {
        if constexpr (F32OUT) Cf[(size_t)(row + r) * ldc + col] = acc[mi][ni][r];
        else                  Cb[(size_t)(row + r) * ldc + col] = f2bf(acc[mi][ni][r]);
      }
    }
}

// ---------- 4. scatter: Q=[qt|qs]*scale, K=[kt+lts*ks | lst*kt+lss*ks] ----------
// Qb linear [B][H][S][128]; Kb SAME but 16B chunks XOR-swizzled by (s&7) within
// each 64-elem half, so attn can global_load_lds it linearly and read swizzled.
__global__ __launch_bounds__(256) void scatter_qk(const ushort* __restrict__ Ct,
                                                  const ushort* __restrict__ Cs,
                                                  ushort* __restrict__ Qb,
                                                  ushort* __restrict__ Kb,
                                                  const float* plts, const float* plst,
                                                  const float* plss) {
  int tid = blockIdx.x * 256 + threadIdx.x;   // 8192 * 128
  int m = tid >> 7, u = tid & 127;
  int b = m >> 11, s = m & 2047;
  int h = u >> 3, din = (u & 7) * 8;
  float lts = plts[0], lst = plst[0], lss = plss[0];
  const float scale = 0.125f;                 // 1/sqrt(64)
  short8 qt = *(const short8*)&Ct[(size_t)m * 3072 + u * 8];
  short8 kt = *(const short8*)&Ct[(size_t)m * 3072 + 1024 + u * 8];
  short8 qs = *(const short8*)&Cs[(size_t)m * 2048 + u * 8];
  short8 ks = *(const short8*)&Cs[(size_t)m * 2048 + 1024 + u * 8];
  short8 oqt, oqs, k1, k2;
#pragma unroll
  for (int j = 0; j < 8; ++j) {
    float fqt = bf2f((ushort)qt[j]), fqs = bf2f((ushort)qs[j]);
    float fkt = bf2f((ushort)kt[j]), fks = bf2f((ushort)ks[j]);
    oqt[j] = (short)f2bf(fqt * scale);
    oqs[j] = (short)f2bf(fqs * scale);
    k1[j]  = (short)f2bf(fkt + lts * fks);
    k2[j]  = (short)f2bf(lst * fkt + lss * fks);
  }
  size_t base = ((size_t)(b * 16 + h) * 2048 + s) * 128;
  *(short8*)&Qb[base + din]      = oqt;
  *(short8*)&Qb[base + 64 + din] = oqs;
  int c1 = ((u & 7) ^ (s & 7)) * 8;           // swizzled 16B chunk
  *(short8*)&Kb[base + c1]      = k1;
  *(short8*)&Kb[base + 64 + c1] = k2;
}

// ---------- 5. V transpose: Ct vt cols -> Vt [B][H][64][S], chunk-swizzled ----------
__global__ __launch_bounds__(256) void transpose_v(const ushort* __restrict__ Ct,
                                                   ushort* __restrict__ Vt) {
  int bh = blockIdx.y; int s0 = blockIdx.x * 64;
  int b = bh >> 4, h = bh & 15;
  __shared__ ushort t[64][72];
  int tid = threadIdx.x;
#pragma unroll
  for (int j = 0; j < 2; ++j) {
    int c = j * 256 + tid;                 // 512 chunks of 8 elems
    int srow = c >> 3, cc = c & 7;
    *(short8*)&t[srow][cc * 8] =
        *(const short8*)&Ct[(size_t)(b * 2048 + s0 + srow) * 3072 + 2048 + h * 64 + cc * 8];
  }
  __syncthreads();
#pragma unroll
  for (int j = 0; j < 2; ++j) {
    int c = j * 256 + tid;
    int drow = c >> 3, cc = c & 7;
    short8 v;
#pragma unroll
    for (int k = 0; k < 8; ++k) v[k] = t[cc * 8 + k][drow];
    // swizzle: 16B chunk index within this 64-col block XOR (d&7)
    *(short8*)&Vt[((size_t)bh * 64 + drow) * 2048 + s0 + ((cc ^ (drow & 7)) * 8)] = v;
  }
}

// ---------- 6. flash attention (swapped-QK^T, in-register softmax) ----------
// grid (S/64, B*H); 4 waves, wave w owns q rows q0+w*16..+16; KV tile 64.
// sK/sV staged via global_load_lds from pre-swizzled Kb/Vt; reads XOR-deswizzle.
__global__ __launch_bounds__(256) void attn_kernel(const ushort* __restrict__ Q,
                                                   const ushort* __restrict__ K,
                                                   const ushort* __restrict__ V,
                                                   ushort* __restrict__ Y) {
  const int bh = blockIdx.y;
  const int q0 = blockIdx.x * 64;
  const int tid = threadIdx.x;
  const int wave = tid >> 6, lane = tid & 63;
  const int l15 = lane & 15, l4 = lane >> 4;
  const int pbit = l4 >> 1, qbit = l4 & 1;
  const size_t qkb = (size_t)bh * 2048 * 128;
  const size_t vb  = (size_t)bh * 64 * 2048;

  __shared__ ushort sK[64 * 128];   // swizzled tile, linear layout
  __shared__ ushort sV[64 * 64];    // swizzled tile, linear layout

  short8 qf[4];
  {
    int qrow = q0 + wave * 16 + l15;
#pragma unroll
    for (int kk = 0; kk < 4; ++kk)
      qf[kk] = *(const short8*)&Q[qkb + (size_t)qrow * 128 + kk * 32 + l4 * 8];
  }
  const f32x4 z = {0.f, 0.f, 0.f, 0.f};
  f32x4 accO[4] = {z, z, z, z};
  float mrow = -3.0e38f, lrow = 0.f;

  for (int kv0 = 0; kv0 < 2048; kv0 += 64) {
    __syncthreads();                        // prev tile's readers done
#pragma unroll
    for (int j = 0; j < 4; ++j) {           // stage K: 64 rows x 256B
      int base = j * 256 + wave * 64;
      int c = base + lane, row = c >> 4, cc = c & 15;
      gload16(&K[qkb + (size_t)(kv0 + row) * 128 + cc * 8], &sK[base * 8]);
    }
#pragma unroll
    for (int j = 0; j < 2; ++j) {           // stage V: 64 rows x 128B
      int base = j * 256 + wave * 64;
      int c = base + lane, row = c >> 3, cc = c & 7;
      gload16(&V[vb + (size_t)row * 2048 + kv0 + cc * 8], &sV[base * 8]);
    }
    __syncthreads();                        // drains vmcnt

    // QK^T swapped: A=K rows(kv), B=Q cols(q). Lane: q=l15, kv=kb*16+l4*4+r
    f32x4 sc[4] = {z, z, z, z};
#pragma unroll
    for (int kk = 0; kk < 4; ++kk)
#pragma unroll
      for (int kb = 0; kb < 4; ++kb) {
        int row = kb * 16 + l15;
        const short8 kf = *(const short8*)&sK[row * 128 + (((kk * 4 + l4) ^ (row & 7)) * 8)];
        sc[kb] = __builtin_amdgcn_mfma_f32_16x16x32_bf16(kf, qf[kk], sc[kb], 0, 0, 0);
      }

    // in-register online softmax for row q=l15 (16 vals/lane, x4 lanes via l4)
    float mx = sc[0][0];
#pragma unroll
    for (int kb = 0; kb < 4; ++kb)
#pragma unroll
      for (int r = 0; r < 4; ++r) mx = fmaxf(mx, sc[kb][r]);
    mx = fmaxf(mx, __shfl_xor(mx, 16));
    mx = fmaxf(mx, __shfl_xor(mx, 32));
    float mnew = fmaxf(mrow, mx);
    float corr = __expf(mrow - mnew);
    mrow = mnew;
    float ps = 0.f;
#pragma unroll
    for (int kb = 0; kb < 4; ++kb)
#pragma unroll
      for (int r = 0; r < 4; ++r) {
        float e = __expf(sc[kb][r] - mnew);
        sc[kb][r] = e; ps += e;
      }
    lrow = lrow * corr + ps;                // per-lane partial (disjoint kv)

    // rescale accO: output row q = l4*4+r needs corr from lane l15=q
#pragma unroll
    for (int r = 0; r < 4; ++r) {
      float cq = __shfl(corr, l4 * 4 + r);
#pragma unroll
      for (int nf = 0; nf < 4; ++nf) accO[nf][r] *= cq;
    }

    // pack P -> bf16 pairs u[kb=(k1,k0)][h]; kv = kb*16 + l4*4 + 2h+{0,1}
    uint u00, u01, u10, u11, u20, u21, u30, u31;
#define CVTPK(d, a, b) asm("v_cvt_pk_bf16_f32 %0, %1, %2" : "=v"(d) : "v"(a), "v"(b))
    CVTPK(u00, sc[0][0], sc[0][1]); CVTPK(u01, sc[0][2], sc[0][3]);
    CVTPK(u10, sc[1][0], sc[1][1]); CVTPK(u11, sc[1][2], sc[1][3]);
    CVTPK(u20, sc[2][0], sc[2][1]); CVTPK(u21, sc[2][2], sc[2][3]);
    CVTPK(u30, sc[3][0], sc[3][1]); CVTPK(u31, sc[3][2], sc[3][3]);
#undef CVTPK
    // butterfly 1 (xor 32): swap lane-bit p (l4>>1) with kb-bit k0
    uint v000, v010, v001, v011, v100, v110, v101, v111;  // v[k1][beta][h]
    {
      uint keep, give, recv;
      keep = pbit ? u10 : u00; give = pbit ? u00 : u10;
      recv = __shfl_xor(give, 32);
      v000 = pbit ? recv : keep; v010 = pbit ? keep : recv;
      keep = pbit ? u11 : u01; give = pbit ? u01 : u11;
      recv = __shfl_xor(give, 32);
      v001 = pbit ? recv : keep; v011 = pbit ? keep : recv;
      keep = pbit ? u30 : u20; give = pbit ? u20 : u30;
      recv = __shfl_xor(give, 32);
      v100 = pbit ? recv : keep; v110 = pbit ? keep : recv;
      keep = pbit ? u31 : u21; give = pbit ? u21 : u31;
      recv = __shfl_xor(give, 32);
      v101 = pbit ? recv : keep; v111 = pbit ? keep : recv;
    }
    // butterfly 2 (xor 16): swap lane-bit q (l4&1) with beta
    uint w000, w010, w001, w011, w100, w110, w101, w111;  // w[ks][gamma][h]
    {
      uint keep, give, recv;
      keep = qbit ? v010 : v000; give = qbit ? v000 : v010;
      recv = __shfl_xor(give, 16);
      w000 = qbit ? recv : keep; w010 = qbit ? keep : recv;
      keep = qbit ? v011 : v001; give = qbit ? v001 : v011;
      recv = __shfl_xor(give, 16);
      w001 = qbit ? recv : keep; w011 = qbit ? keep : recv;
      keep = qbit ? v110 : v100; give = qbit ? v100 : v110;
      recv = __shfl_xor(give, 16);
      w100 = qbit ? recv : keep; w110 = qbit ? keep : recv;
      keep = qbit ? v111 : v101; give = qbit ? v101 : v111;
      recv = __shfl_xor(give, 16);
      w101 = qbit ? recv : keep; w111 = qbit ? keep : recv;
    }
    // assemble PV A-frags: paf[ks][j] = P[q=l15][kv=ks*32+l4*8+j]
    union { uint u4[4]; short8 s8; } pa0, pa1;
    pa0.u4[0] = w000; pa0.u4[1] = w001; pa0.u4[2] = w010; pa0.u4[3] = w011;
    pa1.u4[0] = w100; pa1.u4[1] = w101; pa1.u4[2] = w110; pa1.u4[3] = w111;

    // PV: B-frag from sV (row d, chunk ks*4+l4 deswizzled)
#pragma unroll
    for (int nf = 0; nf < 4; ++nf) {
      int d = nf * 16 + l15;
      const short8 vf0 = *(const short8*)&sV[d * 64 + ((l4 ^ (d & 7)) * 8)];
      accO[nf] = __builtin_amdgcn_mfma_f32_16x16x32_bf16(pa0.s8, vf0, accO[nf], 0, 0, 0);
      const short8 vf1 = *(const short8*)&sV[d * 64 + (((4 + l4) ^ (d & 7)) * 8)];
      accO[nf] = __builtin_amdgcn_mfma_f32_16x16x32_bf16(pa1.s8, vf1, accO[nf], 0, 0, 0);
    }
  }

  // final 1/l ; lane's lrow is a disjoint-kv partial for q=l15
  float ls = lrow + __shfl_xor(lrow, 16);
  ls += __shfl_xor(ls, 32);
  float linv = 1.f / ls;
  int b = bh >> 4, hh = bh & 15;
#pragma unroll
  for (int r = 0; r < 4; ++r) {
    float lq = __shfl(linv, l4 * 4 + r);
    int q = q0 + wave * 16 + l4 * 4 + r;
#pragma unroll
    for (int nf = 0; nf < 4; ++nf)
      Y[((size_t)b * 2048 + q) * 1024 + hh * 64 + nf * 16 + l15] =
          f2bf(accO[nf][r] * lq);
  }
}

// ---------- launcher ----------
extern "C" void kernel_launch(void* const* d_in, const int* in_sizes, int n_in,
                              void* d_out, int out_size, void* d_ws, size_t ws_size,
                              hipStream_t stream) {
  const float* x   = (const float*)d_in[0];
  const float* Wt  = (const float*)d_in[1];
  const float* Ws  = (const float*)d_in[2];
  const float* Wo  = (const float*)d_in[3];
  const float* lts = (const float*)d_in[4];
  const float* lst = (const float*)d_in[5];
  const float* lss = (const float*)d_in[6];
  float* out = (float*)d_out;
  char* ws = (char*)d_ws;

  ushort* xt    = (ushort*)(ws + 0);           // 16,777,216
  ushort* xs    = (ushort*)(ws + 16777216);    // 16,777,216
  ushort* Qbuf  = (ushort*)(ws + 0);           // 33,554,432 (alias, xt/xs dead)
  ushort* Wt_bt = (ushort*)(ws + 33554432);    //  6,291,456
  ushort* Ws_bt = (ushort*)(ws + 39845888);    //  4,194,304
  ushort* Wo_bt = (ushort*)(ws + 44040192);    //  2,097,152
  ushort* Ct    = (ushort*)(ws + 46137344);    // 50,331,648
  ushort* Ybuf  = (ushort*)(ws + 46137344);    // 16,777,216 (alias, Ct head dead)
  ushort* Cs    = (ushort*)(ws + 96468992);    // 33,554,432
  ushort* Kbuf  = (ushort*)(ws + 130023424);   // 33,554,432
  ushort* Vtbuf = (ushort*)(ws + 163577856);   // 16,777,216  -> total 180,355,072
  (void)in_sizes; (void)n_in; (void)out_size; (void)ws_size;

  prep_x<<<8192, 256, 0, stream>>>(x, xt, xs, out);
  transpose_w<<<dim3(96, 32), 256, 0, stream>>>(Wt, Wt_bt, 1024, 3072);
  transpose_w<<<dim3(64, 32), 256, 0, stream>>>(Ws, Ws_bt, 1024, 2048);
  transpose_w<<<dim3(32, 32), 256, 0, stream>>>(Wo, Wo_bt, 1024, 1024);
  gemm_bt<0><<<dim3(24, 64), 256, 0, stream>>>(xt, Wt_bt, Ct, nullptr, 3072, 3072);
  gemm_bt<0><<<dim3(16, 64), 256, 0, stream>>>(xs, Ws_bt, Cs, nullptr, 2048, 2048);
  scatter_qk<<<4096, 256, 0, stream>>>(Ct, Cs, Qbuf, Kbuf, lts, lst, lss);
  transpose_v<<<dim3(32, 64), 256, 0, stream>>>(Ct, Vtbuf);
  attn_kernel<<<dim3(32, 64), 256, 0, stream>>>(Qbuf, Kbuf, Vtbuf, Ybuf);
  gemm_bt<1><<<dim3(8, 64), 256, 0, stream>>>(Ybuf, Wo_bt, nullptr, out, 1024, 2048);
}

// Round 3
// 358.942 us; speedup vs baseline: 1.2974x; 1.1255x over previous
//
#include <hip/hip_runtime.h>

// ---------- types ----------
typedef short  short8  __attribute__((ext_vector_type(8)));   // 8 x bf16 payload (4 VGPR)
typedef float  f32x4   __attribute__((ext_vector_type(4)));
typedef ushort u16x4   __attribute__((ext_vector_type(4)));

__device__ __forceinline__ float bf2f(ushort u) {
  union { unsigned u; float f; } v; v.u = ((unsigned)u) << 16; return v.f;
}
__device__ __forceinline__ ushort f2bf(float f) {
  union { float f; unsigned u; } v; v.f = f;
  unsigned r = v.u + 0x7FFF + ((v.u >> 16) & 1);   // RNE
  return (ushort)(r >> 16);
}
__device__ __forceinline__ float exp2_fast(float x) {   // raw v_exp_f32 (base-2)
  float r; asm("v_exp_f32 %0, %1" : "=v"(r) : "v"(x)); return r;
}

// async global->LDS, 16B per lane; LDS dest = wave-uniform base + lane*16
__device__ __forceinline__ void gload16(const ushort* g, ushort* l) {
  __builtin_amdgcn_global_load_lds(
      (__attribute__((address_space(1))) void*)(void*)(const_cast<ushort*>(g)),
      (__attribute__((address_space(3))) void*)(void*)l, 16, 0, 0);
}

// ---------- sizes ----------
// B=4 S=2048 E=1024 H=16 D=64 ; M = B*S = 8192 ; K = 1024

// ---------- 1. prep: x -> xt,xs bf16 ; out plane1 = xs fp32 ----------
__global__ __launch_bounds__(256) void prep_x(const float* __restrict__ x,
                                              ushort* __restrict__ xt,
                                              ushort* __restrict__ xs,
                                              float* __restrict__ out) {
  size_t i = ((size_t)blockIdx.x * 256 + threadIdx.x) * 4;   // over 8192*1024
  size_t m = i >> 10, e = i & 1023;
  f32x4 a = *(const f32x4*)&x[m * 2048 + e];          // xt row (plane 0)
  f32x4 b = *(const f32x4*)&x[m * 2048 + 1024 + e];   // xs row (plane 1)
  u16x4 ta, tb;
#pragma unroll
  for (int j = 0; j < 4; ++j) { ta[j] = f2bf(a[j]); tb[j] = f2bf(b[j]); }
  *(u16x4*)&xt[i] = ta;
  *(u16x4*)&xs[i] = tb;
  *(f32x4*)&out[m * 2048 + 1024 + e] = b;             // exact passthrough
}

// ---------- 2. weight transpose: W [K][N] f32 -> Wt [N][K] bf16 ----------
__global__ __launch_bounds__(256) void transpose_w(const float* __restrict__ W,
                                                   ushort* __restrict__ Wt,
                                                   int K, int N) {
  __shared__ float tile[32][33];
  int n0 = blockIdx.x * 32, k0 = blockIdx.y * 32;
  int tx = threadIdx.x & 31, ty = threadIdx.x >> 5;   // 32 x 8
#pragma unroll
  for (int i = 0; i < 32; i += 8)
    tile[ty + i][tx] = W[(size_t)(k0 + ty + i) * N + n0 + tx];
  __syncthreads();
#pragma unroll
  for (int i = 0; i < 32; i += 8)
    Wt[(size_t)(n0 + ty + i) * K + k0 + tx] = f2bf(tile[tx][ty + i]);
}

// ---------- 3. GEMM (m97 structure): C[m][n] = sum_k A[m][k]*Bt[n][k] ----------
template <int F32OUT>
__global__ __launch_bounds__(256) void gemm_bt(const ushort* __restrict__ A,
                                               const ushort* __restrict__ Bt,
                                               ushort* __restrict__ Cb,
                                               float* __restrict__ Cf,
                                               int N, int ldc) {
  const int K = 1024;
  __shared__ ushort sA[128 * 32];
  __shared__ ushort sB[128 * 32];
  const int tid = threadIdx.x;
  const int wave = tid >> 6, lane = tid & 63;
  const int wr = wave >> 1, wc = wave & 1;
  const int l15 = lane & 15, l4 = lane >> 4;
  const int m0 = blockIdx.y * 128, n0 = blockIdx.x * 128;

  f32x4 acc[4][4];
  const f32x4 z = {0.f, 0.f, 0.f, 0.f};
#pragma unroll
  for (int a = 0; a < 4; ++a)
#pragma unroll
    for (int b = 0; b < 4; ++b) acc[a][b] = z;

  for (int k0 = 0; k0 < K; k0 += 32) {
#pragma unroll
    for (int j = 0; j < 2; ++j) {
      int cb = j * 256 + wave * 64;       // uniform chunk base
      int c = cb + lane;
      int row = c >> 2, cc = c & 3;       // 4 x 16B chunks per 32-elem row
      gload16(&A [(size_t)(m0 + row) * K + k0 + cc * 8], &sA[cb * 8]);
      gload16(&Bt[(size_t)(n0 + row) * K + k0 + cc * 8], &sB[cb * 8]);
    }
    __syncthreads();                      // drains vmcnt -> LDS valid
    short8 af[4], bfr[4];
#pragma unroll
    for (int i = 0; i < 4; ++i) {
      af[i]  = *(const short8*)&sA[(wr * 64 + i * 16 + l15) * 32 + l4 * 8];
      bfr[i] = *(const short8*)&sB[(wc * 64 + i * 16 + l15) * 32 + l4 * 8];
    }
#pragma unroll
    for (int mi = 0; mi < 4; ++mi)
#pragma unroll
      for (int ni = 0; ni < 4; ++ni)
        acc[mi][ni] = __builtin_amdgcn_mfma_f32_16x16x32_bf16(af[mi], bfr[ni], acc[mi][ni], 0, 0, 0);
    __syncthreads();                      // all reads done before restage
  }

#pragma unroll
  for (int mi = 0; mi < 4; ++mi)
#pragma unroll
    for (int ni = 0; ni < 4; ++ni) {
      int row = m0 + wr * 64 + mi * 16 + l4 * 4;
      int col = n0 + wc * 64 + ni * 16 + l15;
#pragma unroll
      for (int r = 0; r < 4; ++r) {
        if constexpr (F32OUT) Cf[(size_t)(row + r) * ldc + col] = acc[mi][ni][r];
        else                  Cb[(size_t)(row + r) * ldc + col] = f2bf(acc[mi][ni][r]);
      }
    }
}

// ---------- 4. scatter: Q=[qt|qs]*scale*log2e, K=[kt+lts*ks | lst*kt+lss*ks] --
// Qb linear [B][H][S][128]; Kb same but 16B chunks XOR-swizzled by (s&7) within
// each 64-elem half, so attn can global_load_lds it linearly and read swizzled.
__global__ __launch_bounds__(256) void scatter_qk(const ushort* __restrict__ Ct,
                                                  const ushort* __restrict__ Cs,
                                                  ushort* __restrict__ Qb,
                                                  ushort* __restrict__ Kb,
                                                  const float* plts, const float* plst,
                                                  const float* plss) {
  int tid = blockIdx.x * 256 + threadIdx.x;   // 8192 * 128
  int m = tid >> 7, u = tid & 127;
  int b = m >> 11, s = m & 2047;
  int h = u >> 3, din = (u & 7) * 8;
  float lts = plts[0], lst = plst[0], lss = plss[0];
  const float scale = 0.125f * 1.44269504f;   // 1/sqrt(64) * log2(e): exp2 space
  short8 qt = *(const short8*)&Ct[(size_t)m * 3072 + u * 8];
  short8 kt = *(const short8*)&Ct[(size_t)m * 3072 + 1024 + u * 8];
  short8 qs = *(const short8*)&Cs[(size_t)m * 2048 + u * 8];
  short8 ks = *(const short8*)&Cs[(size_t)m * 2048 + 1024 + u * 8];
  short8 oqt, oqs, k1, k2;
#pragma unroll
  for (int j = 0; j < 8; ++j) {
    float fqt = bf2f((ushort)qt[j]), fqs = bf2f((ushort)qs[j]);
    float fkt = bf2f((ushort)kt[j]), fks = bf2f((ushort)ks[j]);
    oqt[j] = (short)f2bf(fqt * scale);
    oqs[j] = (short)f2bf(fqs * scale);
    k1[j]  = (short)f2bf(fkt + lts * fks);
    k2[j]  = (short)f2bf(lst * fkt + lss * fks);
  }
  size_t base = ((size_t)(b * 16 + h) * 2048 + s) * 128;
  *(short8*)&Qb[base + din]      = oqt;
  *(short8*)&Qb[base + 64 + din] = oqs;
  int c1 = ((u & 7) ^ (s & 7)) * 8;           // swizzled 16B chunk
  *(short8*)&Kb[base + c1]      = k1;
  *(short8*)&Kb[base + 64 + c1] = k2;
}

// ---------- 5. V transpose: Ct vt cols -> Vt [B][H][64][S], chunk-swizzled ----
__global__ __launch_bounds__(256) void transpose_v(const ushort* __restrict__ Ct,
                                                   ushort* __restrict__ Vt) {
  int bh = blockIdx.y; int s0 = blockIdx.x * 64;
  int b = bh >> 4, h = bh & 15;
  __shared__ ushort t[64][72];
  int tid = threadIdx.x;
#pragma unroll
  for (int j = 0; j < 2; ++j) {
    int c = j * 256 + tid;                 // 512 chunks of 8 elems
    int srow = c >> 3, cc = c & 7;
    *(short8*)&t[srow][cc * 8] =
        *(const short8*)&Ct[(size_t)(b * 2048 + s0 + srow) * 3072 + 2048 + h * 64 + cc * 8];
  }
  __syncthreads();
#pragma unroll
  for (int j = 0; j < 2; ++j) {
    int c = j * 256 + tid;
    int drow = c >> 3, cc = c & 7;
    short8 v;
#pragma unroll
    for (int k = 0; k < 8; ++k) v[k] = t[cc * 8 + k][drow];
    *(short8*)&Vt[((size_t)bh * 64 + drow) * 2048 + s0 + ((cc ^ (drow & 7)) * 8)] = v;
  }
}

// ---------- 6. flash attention: swapped QK^T, in-reg softmax, 2-phase dbuf ----
// grid 2048 (XCD-swizzled); 4 waves, wave w owns q rows q0+w*16..+16; KV tile 64.
__global__ __launch_bounds__(256) void attn_kernel(const ushort* __restrict__ Q,
                                                   const ushort* __restrict__ Kg,
                                                   const ushort* __restrict__ Vg,
                                                   ushort* __restrict__ Y) {
  // XCD swizzle: same-bh blocks land on same XCD (2048 % 8 == 0 -> bijective)
  const int id   = blockIdx.x;
  const int virt = (id & 7) * 256 + (id >> 3);
  const int bh = virt >> 5;
  const int q0 = (virt & 31) * 64;
  const int tid = threadIdx.x;
  const int wave = tid >> 6, lane = tid & 63;
  const int l15 = lane & 15, l4 = lane >> 4;
  const size_t qkb = (size_t)bh * 2048 * 128;
  const size_t vb  = (size_t)bh * 64 * 2048;

  __shared__ ushort sKV[2 * 64 * 128 + 2 * 64 * 64];   // K dbuf | V dbuf (48 KiB)
  ushort* const sK0 = sKV;
  ushort* const sV0 = sKV + 2 * 64 * 128;

  auto stage = [&](int kv0, int bufi) {
    ushort* dK = sK0 + bufi * (64 * 128);
    ushort* dV = sV0 + bufi * (64 * 64);
#pragma unroll
    for (int j = 0; j < 4; ++j) {           // K tile 64x128 (pre-swizzled)
      int base = j * 256 + wave * 64;
      int c = base + lane, row = c >> 4, cc = c & 15;
      gload16(&Kg[qkb + (size_t)(kv0 + row) * 128 + cc * 8], &dK[base * 8]);
    }
#pragma unroll
    for (int j = 0; j < 2; ++j) {           // V tile [64d][64s] (pre-swizzled)
      int base = j * 256 + wave * 64;
      int c = base + lane, row = c >> 3, cc = c & 7;
      gload16(&Vg[vb + (size_t)row * 2048 + kv0 + cc * 8], &dV[base * 8]);
    }
  };

  short8 qf[4];
  {
    int qrow = q0 + wave * 16 + l15;
#pragma unroll
    for (int kk = 0; kk < 4; ++kk)
      qf[kk] = *(const short8*)&Q[qkb + (size_t)qrow * 128 + kk * 32 + l4 * 8];
  }
  const f32x4 z = {0.f, 0.f, 0.f, 0.f};
  f32x4 accO[4] = {z, z, z, z};
  float mrow = -3.0e38f, lrow = 0.f;

  stage(0, 0);
  __syncthreads();

  for (int t = 0; t < 32; ++t) {
    const int cur = t & 1;
    if (t < 31) stage((t + 1) * 64, cur ^ 1);   // prefetch overlaps compute
    const ushort* cK = sK0 + cur * (64 * 128);
    const ushort* cV = sV0 + cur * (64 * 64);

    // QK^T swapped: A=K rows(kv), B=Q cols(q). Lane: q=l15, kv=kb*16+l4*4+r
    f32x4 sc[4] = {z, z, z, z};
    __builtin_amdgcn_s_setprio(1);
#pragma unroll
    for (int kk = 0; kk < 4; ++kk)
#pragma unroll
      for (int kb = 0; kb < 4; ++kb) {
        int row = kb * 16 + l15;
        const short8 kf = *(const short8*)&cK[row * 128 + (((kk * 4 + l4) ^ (row & 7)) * 8)];
        sc[kb] = __builtin_amdgcn_mfma_f32_16x16x32_bf16(kf, qf[kk], sc[kb], 0, 0, 0);
      }
    __builtin_amdgcn_s_setprio(0);

    // tile max for row q=l15 (16 vals/lane, reduce over l4 pairs)
    float mx = sc[0][0];
#pragma unroll
    for (int kb = 0; kb < 4; ++kb)
#pragma unroll
      for (int r = 0; r < 4; ++r) mx = fmaxf(mx, sc[kb][r]);
    mx = fmaxf(mx, __shfl_xor(mx, 16));
    mx = fmaxf(mx, __shfl_xor(mx, 32));

    // defer-max (T13): rescale only when max grows by > 8 (log2 space)
    if (__any(mx > mrow + 8.f)) {
      float mnew = fmaxf(mrow, mx);
      float corr = exp2_fast(mrow - mnew);
      mrow = mnew;
      lrow *= corr;
#pragma unroll
      for (int r = 0; r < 4; ++r) {
        float cq = __shfl(corr, l4 * 4 + r);
#pragma unroll
        for (int nf = 0; nf < 4; ++nf) accO[nf][r] *= cq;
      }
    }

    float ps = 0.f;
#pragma unroll
    for (int kb = 0; kb < 4; ++kb)
#pragma unroll
      for (int r = 0; r < 4; ++r) {
        float e = exp2_fast(sc[kb][r] - mrow);
        sc[kb][r] = e; ps += e;
      }
    lrow += ps;                              // per-lane partial (disjoint kv)

    // pack P -> bf16 pairs u[kb][h]; kv = kb*16 + l4*4 + 2h+{0,1}
    uint u00, u01, u10, u11, u20, u21, u30, u31;
#define CVTPK(d, a, b) asm("v_cvt_pk_bf16_f32 %0, %1, %2" : "=v"(d) : "v"(a), "v"(b))
    CVTPK(u00, sc[0][0], sc[0][1]); CVTPK(u01, sc[0][2], sc[0][3]);
    CVTPK(u10, sc[1][0], sc[1][1]); CVTPK(u11, sc[1][2], sc[1][3]);
    CVTPK(u20, sc[2][0], sc[2][1]); CVTPK(u21, sc[2][2], sc[2][3]);
    CVTPK(u30, sc[3][0], sc[3][1]); CVTPK(u31, sc[3][2], sc[3][3]);
#undef CVTPK
    // butterfly 1: lane-bit5 <-> kb-bit0  (v_permlane32_swap: dst.hi <-> src.lo)
    asm volatile("v_permlane32_swap_b32 %0, %1" : "+v"(u00), "+v"(u10));
    asm volatile("v_permlane32_swap_b32 %0, %1" : "+v"(u01), "+v"(u11));
    asm volatile("v_permlane32_swap_b32 %0, %1" : "+v"(u20), "+v"(u30));
    asm volatile("v_permlane32_swap_b32 %0, %1" : "+v"(u21), "+v"(u31));
    // butterfly 2: lane-bit4 <-> beta    (v_permlane16_swap: rows 1,3 <-> 0,2)
    asm volatile("v_permlane16_swap_b32 %0, %1" : "+v"(u00), "+v"(u10));
    asm volatile("v_permlane16_swap_b32 %0, %1" : "+v"(u01), "+v"(u11));
    asm volatile("v_permlane16_swap_b32 %0, %1" : "+v"(u20), "+v"(u30));
    asm volatile("v_permlane16_swap_b32 %0, %1" : "+v"(u21), "+v"(u31));
    // assemble PV A-frags: pa[ks].u4[g*2+h] ; P[q=l15][kv=ks*32+l4*8+j]
    union { uint u4[4]; short8 s8; } pa0, pa1;
    pa0.u4[0] = u00; pa0.u4[1] = u01; pa0.u4[2] = u10; pa0.u4[3] = u11;
    pa1.u4[0] = u20; pa1.u4[1] = u21; pa1.u4[2] = u30; pa1.u4[3] = u31;

    // PV: B-frag from cV (row d, chunk ks*4+l4 deswizzled)
    __builtin_amdgcn_s_setprio(1);
#pragma unroll
    for (int nf = 0; nf < 4; ++nf) {
      int d = nf * 16 + l15;
      const short8 vf0 = *(const short8*)&cV[d * 64 + ((l4 ^ (d & 7)) * 8)];
      accO[nf] = __builtin_amdgcn_mfma_f32_16x16x32_bf16(pa0.s8, vf0, accO[nf], 0, 0, 0);
      const short8 vf1 = *(const short8*)&cV[d * 64 + (((4 + l4) ^ (d & 7)) * 8)];
      accO[nf] = __builtin_amdgcn_mfma_f32_16x16x32_bf16(pa1.s8, vf1, accO[nf], 0, 0, 0);
    }
    __builtin_amdgcn_s_setprio(0);

    __syncthreads();   // implicit vmcnt(0)+lgkmcnt(0): prefetch landed, reads done
  }

  // final 1/l ; lane's lrow is a disjoint-kv partial for q=l15
  float ls = lrow + __shfl_xor(lrow, 16);
  ls += __shfl_xor(ls, 32);
  float linv = 1.f / ls;
  int b = bh >> 4, hh = bh & 15;
#pragma unroll
  for (int r = 0; r < 4; ++r) {
    float lq = __shfl(linv, l4 * 4 + r);
    int q = q0 + wave * 16 + l4 * 4 + r;
#pragma unroll
    for (int nf = 0; nf < 4; ++nf)
      Y[((size_t)b * 2048 + q) * 1024 + hh * 64 + nf * 16 + l15] =
          f2bf(accO[nf][r] * lq);
  }
}

// ---------- launcher ----------
extern "C" void kernel_launch(void* const* d_in, const int* in_sizes, int n_in,
                              void* d_out, int out_size, void* d_ws, size_t ws_size,
                              hipStream_t stream) {
  const float* x   = (const float*)d_in[0];
  const float* Wt  = (const float*)d_in[1];
  const float* Ws  = (const float*)d_in[2];
  const float* Wo  = (const float*)d_in[3];
  const float* lts = (const float*)d_in[4];
  const float* lst = (const float*)d_in[5];
  const float* lss = (const float*)d_in[6];
  float* out = (float*)d_out;
  char* ws = (char*)d_ws;

  ushort* xt    = (ushort*)(ws + 0);           // 16,777,216
  ushort* xs    = (ushort*)(ws + 16777216);    // 16,777,216
  ushort* Qbuf  = (ushort*)(ws + 0);           // 33,554,432 (alias, xt/xs dead)
  ushort* Wt_bt = (ushort*)(ws + 33554432);    //  6,291,456
  ushort* Ws_bt = (ushort*)(ws + 39845888);    //  4,194,304
  ushort* Wo_bt = (ushort*)(ws + 44040192);    //  2,097,152
  ushort* Ct    = (ushort*)(ws + 46137344);    // 50,331,648
  ushort* Ybuf  = (ushort*)(ws + 46137344);    // 16,777,216 (alias, Ct head dead)
  ushort* Cs    = (ushort*)(ws + 96468992);    // 33,554,432
  ushort* Kbuf  = (ushort*)(ws + 130023424);   // 33,554,432
  ushort* Vtbuf = (ushort*)(ws + 163577856);   // 16,777,216  -> total 180,355,072
  (void)in_sizes; (void)n_in; (void)out_size; (void)ws_size;

  prep_x<<<8192, 256, 0, stream>>>(x, xt, xs, out);
  transpose_w<<<dim3(96, 32), 256, 0, stream>>>(Wt, Wt_bt, 1024, 3072);
  transpose_w<<<dim3(64, 32), 256, 0, stream>>>(Ws, Ws_bt, 1024, 2048);
  transpose_w<<<dim3(32, 32), 256, 0, stream>>>(Wo, Wo_bt, 1024, 1024);
  gemm_bt<0><<<dim3(24, 64), 256, 0, stream>>>(xt, Wt_bt, Ct, nullptr, 3072, 3072);
  gemm_bt<0><<<dim3(16, 64), 256, 0, stream>>>(xs, Ws_bt, Cs, nullptr, 2048, 2048);
  scatter_qk<<<4096, 256, 0, stream>>>(Ct, Cs, Qbuf, Kbuf, lts, lst, lss);
  transpose_v<<<dim3(32, 64), 256, 0, stream>>>(Ct, Vtbuf);
  attn_kernel<<<2048, 256, 0, stream>>>(Qbuf, Kbuf, Vtbuf, Ybuf);
  gemm_bt<1><<<dim3(8, 64), 256, 0, stream>>>(Ybuf, Wo_bt, nullptr, out, 1024, 2048);
}

// Round 4
// 335.394 us; speedup vs baseline: 1.3885x; 1.0702x over previous
//
#include <hip/hip_runtime.h>

// ---------- types ----------
typedef short  short8  __attribute__((ext_vector_type(8)));   // 8 x bf16 payload (4 VGPR)
typedef float  f32x4   __attribute__((ext_vector_type(4)));
typedef ushort u16x4   __attribute__((ext_vector_type(4)));

__device__ __forceinline__ float bf2f(ushort u) {
  union { unsigned u; float f; } v; v.u = ((unsigned)u) << 16; return v.f;
}
__device__ __forceinline__ ushort f2bf(float f) {
  union { float f; unsigned u; } v; v.f = f;
  unsigned r = v.u + 0x7FFF + ((v.u >> 16) & 1);   // RNE
  return (ushort)(r >> 16);
}
__device__ __forceinline__ float exp2_fast(float x) {   // raw v_exp_f32 (base-2)
  float r; asm("v_exp_f32 %0, %1" : "=v"(r) : "v"(x)); return r;
}

// async global->LDS, 16B per lane; LDS dest = wave-uniform base + lane*16
__device__ __forceinline__ void gload16(const ushort* g, ushort* l) {
  __builtin_amdgcn_global_load_lds(
      (__attribute__((address_space(1))) void*)(void*)(const_cast<ushort*>(g)),
      (__attribute__((address_space(3))) void*)(void*)l, 16, 0, 0);
}

// ---------- sizes ----------
// B=4 S=2048 E=1024 H=16 D=64 ; M = B*S = 8192 ; K = 1024

// ---------- 1. prep: x -> xt,xs bf16 ; out plane1 = xs fp32 ----------
__global__ __launch_bounds__(256) void prep_x(const float* __restrict__ x,
                                              ushort* __restrict__ xt,
                                              ushort* __restrict__ xs,
                                              float* __restrict__ out) {
  size_t i = ((size_t)blockIdx.x * 256 + threadIdx.x) * 4;   // over 8192*1024
  size_t m = i >> 10, e = i & 1023;
  f32x4 a = *(const f32x4*)&x[m * 2048 + e];          // xt row (plane 0)
  f32x4 b = *(const f32x4*)&x[m * 2048 + 1024 + e];   // xs row (plane 1)
  u16x4 ta, tb;
#pragma unroll
  for (int j = 0; j < 4; ++j) { ta[j] = f2bf(a[j]); tb[j] = f2bf(b[j]); }
  *(u16x4*)&xt[i] = ta;
  *(u16x4*)&xs[i] = tb;
  *(f32x4*)&out[m * 2048 + 1024 + e] = b;             // exact passthrough
}

// ---------- 2. weight transpose: W [K][N] f32 -> Wt [N][K] bf16 ----------
__global__ __launch_bounds__(256) void transpose_w(const float* __restrict__ W,
                                                   ushort* __restrict__ Wt,
                                                   int K, int N) {
  __shared__ float tile[32][33];
  int n0 = blockIdx.x * 32, k0 = blockIdx.y * 32;
  int tx = threadIdx.x & 31, ty = threadIdx.x >> 5;   // 32 x 8
#pragma unroll
  for (int i = 0; i < 32; i += 8)
    tile[ty + i][tx] = W[(size_t)(k0 + ty + i) * N + n0 + tx];
  __syncthreads();
#pragma unroll
  for (int i = 0; i < 32; i += 8)
    Wt[(size_t)(n0 + ty + i) * K + k0 + tx] = f2bf(tile[tx][ty + i]);
}

// ---------- 3. GEMM (m97 structure): C[m][n] = sum_k A[m][k]*Bt[n][k] ----------
template <int F32OUT>
__global__ __launch_bounds__(256) void gemm_bt(const ushort* __restrict__ A,
                                               const ushort* __restrict__ Bt,
                                               ushort* __restrict__ Cb,
                                               float* __restrict__ Cf,
                                               int N, int ldc) {
  const int K = 1024;
  __shared__ ushort sA[128 * 32];
  __shared__ ushort sB[128 * 32];
  const int tid = threadIdx.x;
  const int wave = tid >> 6, lane = tid & 63;
  const int wr = wave >> 1, wc = wave & 1;
  const int l15 = lane & 15, l4 = lane >> 4;
  const int m0 = blockIdx.y * 128, n0 = blockIdx.x * 128;

  f32x4 acc[4][4];
  const f32x4 z = {0.f, 0.f, 0.f, 0.f};
#pragma unroll
  for (int a = 0; a < 4; ++a)
#pragma unroll
    for (int b = 0; b < 4; ++b) acc[a][b] = z;

  for (int k0 = 0; k0 < K; k0 += 32) {
#pragma unroll
    for (int j = 0; j < 2; ++j) {
      int cb = j * 256 + wave * 64;       // uniform chunk base
      int c = cb + lane;
      int row = c >> 2, cc = c & 3;       // 4 x 16B chunks per 32-elem row
      gload16(&A [(size_t)(m0 + row) * K + k0 + cc * 8], &sA[cb * 8]);
      gload16(&Bt[(size_t)(n0 + row) * K + k0 + cc * 8], &sB[cb * 8]);
    }
    __syncthreads();                      // drains vmcnt -> LDS valid
    short8 af[4], bfr[4];
#pragma unroll
    for (int i = 0; i < 4; ++i) {
      af[i]  = *(const short8*)&sA[(wr * 64 + i * 16 + l15) * 32 + l4 * 8];
      bfr[i] = *(const short8*)&sB[(wc * 64 + i * 16 + l15) * 32 + l4 * 8];
    }
#pragma unroll
    for (int mi = 0; mi < 4; ++mi)
#pragma unroll
      for (int ni = 0; ni < 4; ++ni)
        acc[mi][ni] = __builtin_amdgcn_mfma_f32_16x16x32_bf16(af[mi], bfr[ni], acc[mi][ni], 0, 0, 0);
    __syncthreads();                      // all reads done before restage
  }

#pragma unroll
  for (int mi = 0; mi < 4; ++mi)
#pragma unroll
    for (int ni = 0; ni < 4; ++ni) {
      int row = m0 + wr * 64 + mi * 16 + l4 * 4;
      int col = n0 + wc * 64 + ni * 16 + l15;
#pragma unroll
      for (int r = 0; r < 4; ++r) {
        if constexpr (F32OUT) Cf[(size_t)(row + r) * ldc + col] = acc[mi][ni][r];
        else                  Cb[(size_t)(row + r) * ldc + col] = f2bf(acc[mi][ni][r]);
      }
    }
}

// ---------- 4. scatter: Q=[qt|qs]*scale*log2e, K=[kt+lts*ks | lst*kt+lss*ks] --
// Qb linear [B][H][S][128]; Kb same but 16B chunks XOR-swizzled by (s&7) within
// each 64-elem half, so attn can global_load_lds it linearly and read swizzled.
__global__ __launch_bounds__(256) void scatter_qk(const ushort* __restrict__ Ct,
                                                  const ushort* __restrict__ Cs,
                                                  ushort* __restrict__ Qb,
                                                  ushort* __restrict__ Kb,
                                                  const float* plts, const float* plst,
                                                  const float* plss) {
  int tid = blockIdx.x * 256 + threadIdx.x;   // 8192 * 128
  int m = tid >> 7, u = tid & 127;
  int b = m >> 11, s = m & 2047;
  int h = u >> 3, din = (u & 7) * 8;
  float lts = plts[0], lst = plst[0], lss = plss[0];
  const float scale = 0.125f * 1.44269504f;   // 1/sqrt(64) * log2(e): exp2 space
  short8 qt = *(const short8*)&Ct[(size_t)m * 3072 + u * 8];
  short8 kt = *(const short8*)&Ct[(size_t)m * 3072 + 1024 + u * 8];
  short8 qs = *(const short8*)&Cs[(size_t)m * 2048 + u * 8];
  short8 ks = *(const short8*)&Cs[(size_t)m * 2048 + 1024 + u * 8];
  short8 oqt, oqs, k1, k2;
#pragma unroll
  for (int j = 0; j < 8; ++j) {
    float fqt = bf2f((ushort)qt[j]), fqs = bf2f((ushort)qs[j]);
    float fkt = bf2f((ushort)kt[j]), fks = bf2f((ushort)ks[j]);
    oqt[j] = (short)f2bf(fqt * scale);
    oqs[j] = (short)f2bf(fqs * scale);
    k1[j]  = (short)f2bf(fkt + lts * fks);
    k2[j]  = (short)f2bf(lst * fkt + lss * fks);
  }
  size_t base = ((size_t)(b * 16 + h) * 2048 + s) * 128;
  *(short8*)&Qb[base + din]      = oqt;
  *(short8*)&Qb[base + 64 + din] = oqs;
  int c1 = ((u & 7) ^ (s & 7)) * 8;           // swizzled 16B chunk
  *(short8*)&Kb[base + c1]      = k1;
  *(short8*)&Kb[base + 64 + c1] = k2;
}

// ---------- 5. V transpose: Ct vt cols -> Vt [B][H][64][S], chunk-swizzled ----
__global__ __launch_bounds__(256) void transpose_v(const ushort* __restrict__ Ct,
                                                   ushort* __restrict__ Vt) {
  int bh = blockIdx.y; int s0 = blockIdx.x * 64;
  int b = bh >> 4, h = bh & 15;
  __shared__ ushort t[64][72];
  int tid = threadIdx.x;
#pragma unroll
  for (int j = 0; j < 2; ++j) {
    int c = j * 256 + tid;                 // 512 chunks of 8 elems
    int srow = c >> 3, cc = c & 7;
    *(short8*)&t[srow][cc * 8] =
        *(const short8*)&Ct[(size_t)(b * 2048 + s0 + srow) * 3072 + 2048 + h * 64 + cc * 8];
  }
  __syncthreads();
#pragma unroll
  for (int j = 0; j < 2; ++j) {
    int c = j * 256 + tid;
    int drow = c >> 3, cc = c & 7;
    short8 v;
#pragma unroll
    for (int k = 0; k < 8; ++k) v[k] = t[cc * 8 + k][drow];
    *(short8*)&Vt[((size_t)bh * 64 + drow) * 2048 + s0 + ((cc ^ (drow & 7)) * 8)] = v;
  }
}

// ---------- 6. flash attention: swapped QK^T, QBLK=128 (32 q-rows/wave) -------
// grid 1024 (XCD-swizzled); K tile reused by 2 q-frags -> 2 MFMA per K ds_read.
__global__ __launch_bounds__(256) void attn_kernel(const ushort* __restrict__ Q,
                                                   const ushort* __restrict__ Kg,
                                                   const ushort* __restrict__ Vg,
                                                   ushort* __restrict__ Y) {
  // XCD swizzle: 1024 blocks, 16 consecutive virt per bh share K/V in L2
  const int id   = blockIdx.x;
  const int virt = (id & 7) * 128 + (id >> 3);
  const int bh = virt >> 4;
  const int q0 = (virt & 15) * 128;
  const int tid = threadIdx.x;
  const int wave = tid >> 6, lane = tid & 63;
  const int l15 = lane & 15, l4 = lane >> 4;
  const size_t qkb = (size_t)bh * 2048 * 128;
  const size_t vb  = (size_t)bh * 64 * 2048;

  __shared__ ushort sKV[2 * 64 * 128 + 2 * 64 * 64];   // K dbuf | V dbuf (48 KiB)
  ushort* const sK0 = sKV;
  ushort* const sV0 = sKV + 2 * 64 * 128;

  auto stage = [&](int kv0, int bufi) {
    ushort* dK = sK0 + bufi * (64 * 128);
    ushort* dV = sV0 + bufi * (64 * 64);
#pragma unroll
    for (int j = 0; j < 4; ++j) {           // K tile 64x128 (pre-swizzled)
      int base = j * 256 + wave * 64;
      int c = base + lane, row = c >> 4, cc = c & 15;
      gload16(&Kg[qkb + (size_t)(kv0 + row) * 128 + cc * 8], &dK[base * 8]);
    }
#pragma unroll
    for (int j = 0; j < 2; ++j) {           // V tile [64d][64s] (pre-swizzled)
      int base = j * 256 + wave * 64;
      int c = base + lane, row = c >> 3, cc = c & 7;
      gload16(&Vg[vb + (size_t)row * 2048 + kv0 + cc * 8], &dV[base * 8]);
    }
  };

  short8 qf[2][4];                           // [qi][kk]
#pragma unroll
  for (int qi = 0; qi < 2; ++qi) {
    int qrow = q0 + wave * 32 + qi * 16 + l15;
#pragma unroll
    for (int kk = 0; kk < 4; ++kk)
      qf[qi][kk] = *(const short8*)&Q[qkb + (size_t)qrow * 128 + kk * 32 + l4 * 8];
  }
  const f32x4 z = {0.f, 0.f, 0.f, 0.f};
  f32x4 accO[2][4] = {{z, z, z, z}, {z, z, z, z}};
  float mrow[2] = {-3.0e38f, -3.0e38f}, lrow[2] = {0.f, 0.f};

  stage(0, 0);
  __syncthreads();

  for (int t = 0; t < 32; ++t) {
    const int cur = t & 1;
    if (t < 31) stage((t + 1) * 64, cur ^ 1);   // prefetch overlaps compute
    const ushort* cK = sK0 + cur * (64 * 128);
    const ushort* cV = sV0 + cur * (64 * 64);

    // QK^T swapped: A=K rows(kv), B=Q cols(q). Lane: q=l15, kv=kb*16+l4*4+r
    f32x4 sc[2][4] = {{z, z, z, z}, {z, z, z, z}};
    __builtin_amdgcn_s_setprio(1);
#pragma unroll
    for (int kk = 0; kk < 4; ++kk)
#pragma unroll
      for (int kb = 0; kb < 4; ++kb) {
        int row = kb * 16 + l15;
        const short8 kf = *(const short8*)&cK[row * 128 + (((kk * 4 + l4) ^ (row & 7)) * 8)];
        sc[0][kb] = __builtin_amdgcn_mfma_f32_16x16x32_bf16(kf, qf[0][kk], sc[0][kb], 0, 0, 0);
        sc[1][kb] = __builtin_amdgcn_mfma_f32_16x16x32_bf16(kf, qf[1][kk], sc[1][kb], 0, 0, 0);
      }
    __builtin_amdgcn_s_setprio(0);

    union { uint u4[4]; short8 s8; } pa[2][2];
#pragma unroll
    for (int qi = 0; qi < 2; ++qi) {
      // tile max for row q=l15 (16 vals/lane, reduce over l4 pairs)
      float mx = sc[qi][0][0];
#pragma unroll
      for (int kb = 0; kb < 4; ++kb)
#pragma unroll
        for (int r = 0; r < 4; ++r) mx = fmaxf(mx, sc[qi][kb][r]);
      mx = fmaxf(mx, __shfl_xor(mx, 16));
      mx = fmaxf(mx, __shfl_xor(mx, 32));

      // defer-max (T13): rescale only when max grows by > 8 (log2 space)
      if (__any(mx > mrow[qi] + 8.f)) {
        float mnew = fmaxf(mrow[qi], mx);
        float corr = exp2_fast(mrow[qi] - mnew);
        mrow[qi] = mnew;
        lrow[qi] *= corr;
#pragma unroll
        for (int r = 0; r < 4; ++r) {
          float cq = __shfl(corr, l4 * 4 + r);
#pragma unroll
          for (int nf = 0; nf < 4; ++nf) accO[qi][nf][r] *= cq;
        }
      }

      float ps = 0.f;
#pragma unroll
      for (int kb = 0; kb < 4; ++kb)
#pragma unroll
        for (int r = 0; r < 4; ++r) {
          float e = exp2_fast(sc[qi][kb][r] - mrow[qi]);
          sc[qi][kb][r] = e; ps += e;
        }
      lrow[qi] += ps;                        // per-lane partial (disjoint kv)

      // pack P -> bf16 pairs u[kb][h]; kv = kb*16 + l4*4 + 2h+{0,1}
      uint u00, u01, u10, u11, u20, u21, u30, u31;
#define CVTPK(d, a, b) asm("v_cvt_pk_bf16_f32 %0, %1, %2" : "=v"(d) : "v"(a), "v"(b))
      CVTPK(u00, sc[qi][0][0], sc[qi][0][1]); CVTPK(u01, sc[qi][0][2], sc[qi][0][3]);
      CVTPK(u10, sc[qi][1][0], sc[qi][1][1]); CVTPK(u11, sc[qi][1][2], sc[qi][1][3]);
      CVTPK(u20, sc[qi][2][0], sc[qi][2][1]); CVTPK(u21, sc[qi][2][2], sc[qi][2][3]);
      CVTPK(u30, sc[qi][3][0], sc[qi][3][1]); CVTPK(u31, sc[qi][3][2], sc[qi][3][3]);
#undef CVTPK
      // butterfly 1: lane-bit5 <-> kb-bit0  (v_permlane32_swap)
      asm volatile("v_permlane32_swap_b32 %0, %1" : "+v"(u00), "+v"(u10));
      asm volatile("v_permlane32_swap_b32 %0, %1" : "+v"(u01), "+v"(u11));
      asm volatile("v_permlane32_swap_b32 %0, %1" : "+v"(u20), "+v"(u30));
      asm volatile("v_permlane32_swap_b32 %0, %1" : "+v"(u21), "+v"(u31));
      // butterfly 2: lane-bit4 <-> beta    (v_permlane16_swap)
      asm volatile("v_permlane16_swap_b32 %0, %1" : "+v"(u00), "+v"(u10));
      asm volatile("v_permlane16_swap_b32 %0, %1" : "+v"(u01), "+v"(u11));
      asm volatile("v_permlane16_swap_b32 %0, %1" : "+v"(u20), "+v"(u30));
      asm volatile("v_permlane16_swap_b32 %0, %1" : "+v"(u21), "+v"(u31));
      // assemble PV A-frags: P[q=l15][kv=ks*32+l4*8+j]
      pa[qi][0].u4[0] = u00; pa[qi][0].u4[1] = u01; pa[qi][0].u4[2] = u10; pa[qi][0].u4[3] = u11;
      pa[qi][1].u4[0] = u20; pa[qi][1].u4[1] = u21; pa[qi][1].u4[2] = u30; pa[qi][1].u4[3] = u31;
    }

    // PV: B-frag from cV (row d, chunk ks*4+l4 deswizzled); V frags shared by qi
    __builtin_amdgcn_s_setprio(1);
#pragma unroll
    for (int nf = 0; nf < 4; ++nf) {
      int d = nf * 16 + l15;
      const short8 vf0 = *(const short8*)&cV[d * 64 + ((l4 ^ (d & 7)) * 8)];
      const short8 vf1 = *(const short8*)&cV[d * 64 + (((4 + l4) ^ (d & 7)) * 8)];
      accO[0][nf] = __builtin_amdgcn_mfma_f32_16x16x32_bf16(pa[0][0].s8, vf0, accO[0][nf], 0, 0, 0);
      accO[1][nf] = __builtin_amdgcn_mfma_f32_16x16x32_bf16(pa[1][0].s8, vf0, accO[1][nf], 0, 0, 0);
      accO[0][nf] = __builtin_amdgcn_mfma_f32_16x16x32_bf16(pa[0][1].s8, vf1, accO[0][nf], 0, 0, 0);
      accO[1][nf] = __builtin_amdgcn_mfma_f32_16x16x32_bf16(pa[1][1].s8, vf1, accO[1][nf], 0, 0, 0);
    }
    __builtin_amdgcn_s_setprio(0);

    __syncthreads();   // implicit vmcnt(0)+lgkmcnt(0): prefetch landed, reads done
  }

  int b = bh >> 4, hh = bh & 15;
#pragma unroll
  for (int qi = 0; qi < 2; ++qi) {
    float ls = lrow[qi] + __shfl_xor(lrow[qi], 16);
    ls += __shfl_xor(ls, 32);
    float linv = 1.f / ls;
#pragma unroll
    for (int r = 0; r < 4; ++r) {
      float lq = __shfl(linv, l4 * 4 + r);
      int q = q0 + wave * 32 + qi * 16 + l4 * 4 + r;
#pragma unroll
      for (int nf = 0; nf < 4; ++nf)
        Y[((size_t)b * 2048 + q) * 1024 + hh * 64 + nf * 16 + l15] =
            f2bf(accO[qi][nf][r] * lq);
    }
  }
}

// ---------- launcher ----------
extern "C" void kernel_launch(void* const* d_in, const int* in_sizes, int n_in,
                              void* d_out, int out_size, void* d_ws, size_t ws_size,
                              hipStream_t stream) {
  const float* x   = (const float*)d_in[0];
  const float* Wt  = (const float*)d_in[1];
  const float* Ws  = (const float*)d_in[2];
  const float* Wo  = (const float*)d_in[3];
  const float* lts = (const float*)d_in[4];
  const float* lst = (const float*)d_in[5];
  const float* lss = (const float*)d_in[6];
  float* out = (float*)d_out;
  char* ws = (char*)d_ws;

  ushort* xt    = (ushort*)(ws + 0);           // 16,777,216
  ushort* xs    = (ushort*)(ws + 16777216);    // 16,777,216
  ushort* Qbuf  = (ushort*)(ws + 0);           // 33,554,432 (alias, xt/xs dead)
  ushort* Wt_bt = (ushort*)(ws + 33554432);    //  6,291,456
  ushort* Ws_bt = (ushort*)(ws + 39845888);    //  4,194,304
  ushort* Wo_bt = (ushort*)(ws + 44040192);    //  2,097,152
  ushort* Ct    = (ushort*)(ws + 46137344);    // 50,331,648
  ushort* Ybuf  = (ushort*)(ws + 46137344);    // 16,777,216 (alias, Ct head dead)
  ushort* Cs    = (ushort*)(ws + 96468992);    // 33,554,432
  ushort* Kbuf  = (ushort*)(ws + 130023424);   // 33,554,432
  ushort* Vtbuf = (ushort*)(ws + 163577856);   // 16,777,216  -> total 180,355,072
  (void)in_sizes; (void)n_in; (void)out_size; (void)ws_size;

  prep_x<<<8192, 256, 0, stream>>>(x, xt, xs, out);
  transpose_w<<<dim3(96, 32), 256, 0, stream>>>(Wt, Wt_bt, 1024, 3072);
  transpose_w<<<dim3(64, 32), 256, 0, stream>>>(Ws, Ws_bt, 1024, 2048);
  transpose_w<<<dim3(32, 32), 256, 0, stream>>>(Wo, Wo_bt, 1024, 1024);
  gemm_bt<0><<<dim3(24, 64), 256, 0, stream>>>(xt, Wt_bt, Ct, nullptr, 3072, 3072);
  gemm_bt<0><<<dim3(16, 64), 256, 0, stream>>>(xs, Ws_bt, Cs, nullptr, 2048, 2048);
  scatter_qk<<<4096, 256, 0, stream>>>(Ct, Cs, Qbuf, Kbuf, lts, lst, lss);
  transpose_v<<<dim3(32, 64), 256, 0, stream>>>(Ct, Vtbuf);
  attn_kernel<<<1024, 256, 0, stream>>>(Qbuf, Kbuf, Vtbuf, Ybuf);
  gemm_bt<1><<<dim3(8, 64), 256, 0, stream>>>(Ybuf, Wo_bt, nullptr, out, 1024, 2048);
}